// Round 10
// baseline (66.401 us; speedup 1.0000x reference)
//
#include <hip/hip_runtime.h>
#include <hip/hip_bf16.h>

// x:[16,64,128,128] f32 -> stats -> MLP -> per-sample kern[64,64,3,3] -> conv(pad=1)
// bf16 MFMA implicit GEMM. xT[b][y][130 xi][64 ci] bf16 (x-padded zero cols).
// wT layout: [b][tap(9)][co(64)][64 ci, 16B-slot s stored at s^(co&7)] = conv's
// wls LDS image (pure linear DMA).
// R10: conv re-shaped for 0.5 ds_read/MFMA: wave = 64co x 4rows x 16px
// (4 A-frags x 4 B-frags -> 16 MFMA per (kp,tap)), block = 8 rows x 64 px,
// 512 one-shot blocks, single barrier, no store-drain in any wait.

#define B_ 16
#define NPIX 16384
#define KEL 36864
#define XT_RS 8320          // 130 * 64 shorts per padded row

typedef __attribute__((ext_vector_type(4))) float f32x4;
typedef __attribute__((ext_vector_type(8))) short short8;

static __device__ __forceinline__ short bf16_of(float f) {
    __hip_bfloat16 h = __float2bfloat16(f);
    return *reinterpret_cast<short*>(&h);
}

// ---------- Kernel 1: transpose x -> xT bf16 [b][y][130][64]; partial stats ----------
__global__ __launch_bounds__(256) void xpose_stats(const float* __restrict__ x,
                                                   short* __restrict__ xT,
                                                   float* __restrict__ part) {
    int b = blockIdx.x, cig = blockIdx.y, pt = blockIdx.z;
    int t = threadIdx.x;
    int y = pt * 8 + (t >> 5);
    int x0 = (t & 31) * 4;

    const float* xb = x + ((size_t)(b * 64 + cig * 8)) * NPIX;
    short* xTb = xT + (size_t)b * 128 * XT_RS;

    float s[8], ss[8];
    f32x4 v[8];
    #pragma unroll
    for (int c = 0; c < 8; c++) {
        v[c] = *(const f32x4*)(xb + (size_t)c * NPIX + y * 128 + x0);
        s[c]  = v[c][0] + v[c][1] + v[c][2] + v[c][3];
        ss[c] = v[c][0]*v[c][0] + v[c][1]*v[c][1] + v[c][2]*v[c][2] + v[c][3]*v[c][3];
    }
    #pragma unroll
    for (int xi = 0; xi < 4; xi++) {
        short8 o;
        #pragma unroll
        for (int c = 0; c < 8; c++) o[c] = bf16_of(v[c][xi]);
        *(short8*)(xTb + ((size_t)(y * 130 + x0 + xi + 1)) * 64 + cig * 8) = o;
    }
    // zero-pad columns xi=0 and xi=129 (x halo)
    if (t < 16) {
        int y2 = pt * 8 + (t & 7);
        int col = (t & 8) ? 129 : 0;
        short8 z = {0, 0, 0, 0, 0, 0, 0, 0};
        *(short8*)(xTb + ((size_t)(y2 * 130 + col)) * 64 + cig * 8) = z;
    }

    __shared__ float red[4][16];
    int lane = t & 63, w = t >> 6;
    #pragma unroll
    for (int c = 0; c < 8; c++) {
        float a = s[c], q = ss[c];
        for (int off = 32; off; off >>= 1) { a += __shfl_down(a, off); q += __shfl_down(q, off); }
        if (lane == 0) { red[w][c * 2] = a; red[w][c * 2 + 1] = q; }
    }
    __syncthreads();
    if (t < 16)
        part[((size_t)((b * 8 + cig) * 16 + pt)) * 16 + t] =
            red[0][t] + red[1][t] + red[2][t] + red[3][t];
}

// ---------- Kernel 2: w2 read ONCE; all 16 b per block (grid 144) ----------
__global__ __launch_bounds__(256) void kern_gen(const float* __restrict__ part,
                                                const float* __restrict__ w1,
                                                const float* __restrict__ b1,
                                                const float* __restrict__ w2,
                                                const float* __restrict__ b2,
                                                short* __restrict__ wT) {
    __shared__ float st[16][128];
    __shared__ float hT[32][16];
    int t = threadIdx.x;

    for (int id = t; id < 1024; id += 256) {       // stats for all (b, ci)
        int b = id >> 6, ci = id & 63;
        const float* pb = part + ((size_t)((b * 8 + (ci >> 3)) * 16)) * 16 + (ci & 7) * 2;
        float s = 0.f, q = 0.f;
        #pragma unroll
        for (int p = 0; p < 16; p++) { s += pb[p * 16]; q += pb[p * 16 + 1]; }
        float mean = s * (1.f / NPIX);
        float var = fmaxf((q - s * mean) * (1.f / (NPIX - 1)), 0.f);
        st[b][ci] = mean;
        st[b][64 + ci] = sqrtf(var);
    }
    __syncthreads();
    for (int id = t; id < 512; id += 256) {        // h for all (b, 32), transposed
        int b = id >> 5, jj = id & 31;
        float acc = b1[jj];
        for (int i = 0; i < 128; i++) acc += st[b][i] * w1[i * 32 + jj];
        hT[jj][b] = fmaxf(acc, 0.f);
    }
    __syncthreads();

    int j = blockIdx.x * 256 + t;
    float wv[32];
    #pragma unroll
    for (int i = 0; i < 32; i++) wv[i] = w2[(size_t)i * KEL + j];
    float bv = b2[j];

    float acc[16];
    #pragma unroll
    for (int b = 0; b < 16; b++) acc[b] = bv;
    #pragma unroll
    for (int i = 0; i < 32; i++) {
        float wvi = wv[i];
        const f32x4* hr = (const f32x4*)&hT[i][0];
        #pragma unroll
        for (int q4 = 0; q4 < 4; q4++) {
            f32x4 hq = hr[q4];
            acc[q4 * 4 + 0] += hq[0] * wvi;
            acc[q4 * 4 + 1] += hq[1] * wvi;
            acc[q4 * 4 + 2] += hq[2] * wvi;
            acc[q4 * 4 + 3] += hq[3] * wvi;
        }
    }

    // j = (co*64+ci)*9 + tap; store pre-swizzled: [tap][co][ (ci>>3)^(co&7) slot ]
    int co = j / 576;
    int rem = j - co * 576;
    int ci = rem / 9;
    int tap = rem - ci * 9;
    size_t dst = (size_t)tap * 4096 + co * 64 + ((((ci >> 3) ^ (co & 7)) << 3) | (ci & 7));
    #pragma unroll
    for (int b = 0; b < 16; b++)
        wT[(size_t)b * KEL + dst] = bf16_of(acc[b]);
}

// ---------- Kernel 3: conv via MFMA, 0.5 ds_read/MFMA wave shape ----------
// grid (b=16, xt=2, yo=16) = 512 blocks, 512 thr (8 waves = xq(4) x rh(2)).
// Wave: 64 co x 4 rows x 16 px; per (kp,tap): 4 A + 4 B reads -> 16 MFMA.
// LDS: xls 10 rows x 528 slots x 16B (84480 B) + wls 9x512x16B (73728 B).
// One barrier per block; the only waitcnt precedes all stores (no store drain).
__global__ __launch_bounds__(512, 1) void conv_mfma(const short* __restrict__ xT,
                                                    const short* __restrict__ wT,
                                                    float* __restrict__ out) {
    __shared__ __align__(16) short xls[10 * 528 * 8];   // slot = row*528 + xi*8 + p
    __shared__ __align__(16) short wls[9 * 512 * 8];    // slot = tap*512 + co*8 + p

    int b = blockIdx.x, xt = blockIdx.y, yo = blockIdx.z;
    int x0 = xt * 64, y0 = yo * 8;
    int t = threadIdx.x;
    int l = t & 63, w = t >> 6;
    int xq = w & 3, rh = w >> 2;
    int l15 = l & 15, lg = l >> 4;

    const short* xTb = xT + (size_t)b * 128 * XT_RS;
    const short* wTb = wT + (size_t)b * KEL;

    // ---- stage wls (pure linear DMA, wT is pre-swizzled) ----
    #pragma unroll
    for (int it = 0; it < 9; it++) {
        int e = it * 512 + t;
        __builtin_amdgcn_global_load_lds(
            (const __attribute__((address_space(1))) void*)(wTb + (size_t)e * 8),
            (__attribute__((address_space(3))) void*)(wls + (it * 512 + (t & ~63)) * 8),
            16, 0, 0);
    }
    // ---- stage x rows y0-1 .. y0+8 into slots 0..9 ----
    #pragma unroll
    for (int lr = 0; lr < 10; lr++) {
        int y = y0 - 1 + lr;
        if (y < 0 || y > 127) {
            short8 z8 = {0, 0, 0, 0, 0, 0, 0, 0};
            for (int e = t; e < 528; e += 512)
                *(short8*)(xls + (lr * 528 + e) * 8) = z8;
        } else {
            #pragma unroll
            for (int it = 0; it < 2; it++) {
                int e = it * 512 + t;
                if (e < 528) {
                    int xi = e >> 3, s = e & 7;
                    const short* src = xTb + (size_t)y * XT_RS
                        + (x0 + xi) * 64 + ((s ^ (xi & 7)) << 3);
                    __builtin_amdgcn_global_load_lds(
                        (const __attribute__((address_space(1))) void*)src,
                        (__attribute__((address_space(3))) void*)
                            (xls + (lr * 528 + it * 512 + (t & ~63)) * 8),
                        16, 0, 0);
                }
            }
        }
    }
    asm volatile("s_waitcnt vmcnt(0) lgkmcnt(0)" ::: "memory");
    __builtin_amdgcn_s_barrier();
    __builtin_amdgcn_sched_barrier(0);

    f32x4 acc[4][4];                      // [row r][co-frag g]
    #pragma unroll
    for (int r = 0; r < 4; r++)
        #pragma unroll
        for (int g = 0; g < 4; g++) acc[r][g] = (f32x4){0.f, 0.f, 0.f, 0.f};

    #pragma unroll
    for (int kp = 0; kp < 2; kp++) {
        int sig = kp * 4 + lg;
        int pa = sig ^ (l15 & 7);
        #pragma unroll
        for (int tap = 0; tap < 9; tap++) {
            const int dy = tap / 3, dx = tap % 3;
            short8 a[4], bf[4];
            #pragma unroll
            for (int g = 0; g < 4; g++)
                a[g] = *(const short8*)&wls[(tap * 512 + (g * 16 + l15) * 8 + pa) * 8];
            int xi = xq * 16 + l15 + dx;                    // 0..65
            int sw = sig ^ (xi & 7);
            #pragma unroll
            for (int r = 0; r < 4; r++)
                bf[r] = *(const short8*)&xls[((rh * 4 + r + dy) * 528 + xi * 8 + sw) * 8];
            #pragma unroll
            for (int r = 0; r < 4; r++)
                #pragma unroll
                for (int g = 0; g < 4; g++)
                    acc[r][g] = __builtin_amdgcn_mfma_f32_16x16x32_bf16(a[g], bf[r], acc[r][g], 0, 0, 0);
        }
    }

    // ---- store 4 co-frags x 4 regs x 4 rows ----
    #pragma unroll
    for (int g = 0; g < 4; g++) {
        float* ob = out + ((size_t)(b * 64 + g * 16 + lg * 4)) * NPIX
                        + (y0 + rh * 4) * 128 + x0 + xq * 16 + l15;
        #pragma unroll
        for (int reg = 0; reg < 4; reg++)
            #pragma unroll
            for (int r = 0; r < 4; r++)
                ob[(size_t)reg * NPIX + r * 128] = acc[r][g][reg];
    }
}

extern "C" void kernel_launch(void* const* d_in, const int* in_sizes, int n_in,
                              void* d_out, int out_size, void* d_ws, size_t ws_size,
                              hipStream_t stream) {
    const float* x  = (const float*)d_in[0];
    const float* w1 = (const float*)d_in[1];
    const float* b1 = (const float*)d_in[2];
    const float* w2 = (const float*)d_in[3];
    const float* b2 = (const float*)d_in[4];
    float* out = (float*)d_out;

    float* part = (float*)d_ws;                                   // 128 KB
    short* wT = (short*)((char*)d_ws + 131072);                   // 1.18 MB
    short* xT = (short*)((char*)d_ws + 131072 + 1179648);         // 34.1 MB

    xpose_stats<<<dim3(B_, 8, 16), 256, 0, stream>>>(x, xT, part);
    kern_gen<<<dim3(144), 256, 0, stream>>>(part, w1, b1, w2, b2, wT);
    conv_mfma<<<dim3(B_, 2, 16), 512, 0, stream>>>(xT, wT, out);
}